// Round 3
// baseline (4193.521 us; speedup 1.0000x reference)
//
#include <hip/hip_runtime.h>
#include <hip/hip_bf16.h>
#include <cstdint>
#include <cstddef>

#define BATCH 4096
#define DIM   2048
#define FEAT  16384

typedef __attribute__((ext_vector_type(8))) short s8v;
typedef __attribute__((ext_vector_type(4))) float f4v;

__device__ __forceinline__ unsigned short f2bf(float f){
  unsigned u = __float_as_uint(f);
  unsigned r = u + 0x7FFFu + ((u >> 16) & 1u);
  return (unsigned short)(r >> 16);
}
__device__ __forceinline__ float bf2f(unsigned short h){
  return __uint_as_float(((unsigned)h) << 16);
}
__device__ __forceinline__ void split3(float v, unsigned short &h, unsigned short &m, unsigned short &l){
  h = f2bf(v);
  float r1 = v - bf2f(h);
  m = f2bf(r1);
  float r2 = r1 - bf2f(m);
  l = f2bf(r2);
}

__device__ __forceinline__ void gload16(const void* g, void* l){
  __builtin_amdgcn_global_load_lds(
      (const __attribute__((address_space(1))) void*)g,
      (__attribute__((address_space(3))) void*)l, 16, 0, 0);
}

// ===========================================================================
// PATH A: pre-split planes + global_load_lds GEMM
// ===========================================================================

// x -> 3 bf16 planes of (x - b_dec)
__global__ __launch_bounds__(256)
void splitX(const float* __restrict__ x, const float* __restrict__ bdec,
            unsigned short* __restrict__ p0, unsigned short* __restrict__ p1,
            unsigned short* __restrict__ p2)
{
  const size_t i = ((size_t)blockIdx.x * 256 + threadIdx.x) * 4;
  const int col = (int)(i & (DIM - 1));
  const float4 v = *(const float4*)(x + i);
  const float4 b = *(const float4*)(bdec + col);
  float e0 = v.x - b.x, e1 = v.y - b.y, e2 = v.z - b.z, e3 = v.w - b.w;
  ushort4 H, M, L;
  split3(e0, H.x, M.x, L.x); split3(e1, H.y, M.y, L.y);
  split3(e2, H.z, M.z, L.z); split3(e3, H.w, M.w, L.w);
  *(ushort4*)(p0 + i) = H; *(ushort4*)(p1 + i) = M; *(ushort4*)(p2 + i) = L;
}

// W -> 3 bf16 planes
__global__ __launch_bounds__(256)
void splitW(const float* __restrict__ w,
            unsigned short* __restrict__ p0, unsigned short* __restrict__ p1,
            unsigned short* __restrict__ p2)
{
  const size_t i = ((size_t)blockIdx.x * 256 + threadIdx.x) * 4;
  const float4 v = *(const float4*)(w + i);
  ushort4 H, M, L;
  split3(v.x, H.x, M.x, L.x); split3(v.y, H.y, M.y, L.y);
  split3(v.z, H.z, M.z, L.z); split3(v.w, H.w, M.w, L.w);
  *(ushort4*)(p0 + i) = H; *(ushort4*)(p1 + i) = M; *(ushort4*)(p2 + i) = L;
}

// Plane GEMM: C[row,col] = sum over 6 plane pairs (hh,hm,hl,mh,mm,lh).
// 128x128 tile, BK=32, 4 waves (64x64 per wave), global_load_lds staging,
// XOR-(r&7) group swizzle on 128B LDS rows (pre-swizzled global source).
// Block walk: per XCD, bx is SLOW (16 column-panels per XCD), by FAST
// -> B panel (1.5 MB) stays L2-resident; A panels stream, LLC-shared
//    across XCDs (all XCDs at the same by phase).
template<int MODE>
__global__ __launch_bounds__(256, 2)
void gemmp(const unsigned short* __restrict__ Ah_, const unsigned short* __restrict__ Am_,
           const unsigned short* __restrict__ Al_,
           const unsigned short* __restrict__ Bh_, const unsigned short* __restrict__ Bm_,
           const unsigned short* __restrict__ Bl_,
           const float* __restrict__ bias, const float* __restrict__ w2,
           float* __restrict__ acts, float* __restrict__ zpart)
{
  // [0] = Ah|Am, [1] = Bh|Bm, [2] = Al|Bl   (128 rows x 128 bytes)
  __shared__ unsigned short sAB[3][128][64];
  const int tid  = threadIdx.x;
  const int lane = tid & 63, wv = tid >> 6;

  // bijective XCD-aware mapping: xcd = bid&7 (round-robin dispatch),
  // idx = bid>>3 in [0,512): bx = xcd*16 + idx/32 (slow), by = idx%32 (fast)
  const int bid = blockIdx.x;
  const int xcd = bid & 7;
  const int idx = bid >> 3;
  const int bx  = (xcd << 4) | (idx >> 5);   // 0..127
  const int by  = idx & 31;                  // 0..31
  const int row0 = by << 7, col0 = bx << 7;

  const int wr = (wv & 1) << 6, wc = (wv >> 1) << 6;

  f4v acc[4][4];
  #pragma unroll
  for (int i = 0; i < 4; ++i)
    #pragma unroll
    for (int j = 0; j < 4; ++j)
      acc[i][j] = (f4v){0.f, 0.f, 0.f, 0.f};

  // ---- staging precompute: 3 buffers x 4 issues per thread ----
  const int sr = lane >> 3;   // row within 8-row stripe
  const int gp = lane & 7;    // physical 16B group
  const unsigned short* gsrc[3][4];
  #pragma unroll
  for (int j = 0; j < 4; ++j){
    const int r  = (((wv << 2) + j) << 3) + sr;      // 0..127
    const int gl = gp ^ (r & 7);                     // logical group
    const int co = (gl & 3) << 3;                    // k-element offset
    gsrc[0][j] = ((gl < 4) ? Ah_ : Am_) + (size_t)(row0 + r) * DIM + co;
    gsrc[1][j] = ((gl < 4) ? Bh_ : Bm_) + (size_t)(col0 + r) * DIM + co;
    gsrc[2][j] = (gl < 4) ? (Al_ + (size_t)(row0 + r) * DIM + co)
                          : (Bl_ + (size_t)(col0 + r) * DIM + co);
  }

  const int fr16 = lane & 15;
  const int kg   = lane >> 4;
  int ra[4], rb[4];
  #pragma unroll
  for (int f = 0; f < 4; ++f){ ra[f] = wr + (f << 4) + fr16; rb[f] = wc + (f << 4) + fr16; }

  #define LDFRAG(b, r, hb) (*(const s8v*)&sAB[b][r][(((hb) + kg) ^ ((r) & 7)) << 3])

  for (int kt = 0; kt < DIM / 32; ++kt){
    const int ko = kt << 5;
    #pragma unroll
    for (int b = 0; b < 3; ++b)
      #pragma unroll
      for (int j = 0; j < 4; ++j)
        gload16(gsrc[b][j] + ko, &sAB[b][(((wv << 2) + j) << 3)][0]);
    __syncthreads();

    s8v Ah[4], Am[4], Al[4], Bh[4], Bm[4], Bl[4];
    #pragma unroll
    for (int f = 0; f < 4; ++f) Ah[f] = LDFRAG(0, ra[f], 0);
    #pragma unroll
    for (int f = 0; f < 4; ++f) Bh[f] = LDFRAG(1, rb[f], 0);
    #pragma unroll
    for (int fi = 0; fi < 4; ++fi)
      #pragma unroll
      for (int fj = 0; fj < 4; ++fj)
        acc[fi][fj] = __builtin_amdgcn_mfma_f32_16x16x32_bf16(Ah[fi], Bh[fj], acc[fi][fj], 0, 0, 0);
    #pragma unroll
    for (int f = 0; f < 4; ++f) Bm[f] = LDFRAG(1, rb[f], 4);
    #pragma unroll
    for (int fi = 0; fi < 4; ++fi)
      #pragma unroll
      for (int fj = 0; fj < 4; ++fj)
        acc[fi][fj] = __builtin_amdgcn_mfma_f32_16x16x32_bf16(Ah[fi], Bm[fj], acc[fi][fj], 0, 0, 0);
    #pragma unroll
    for (int f = 0; f < 4; ++f) Bl[f] = LDFRAG(2, rb[f], 4);
    #pragma unroll
    for (int fi = 0; fi < 4; ++fi)
      #pragma unroll
      for (int fj = 0; fj < 4; ++fj)
        acc[fi][fj] = __builtin_amdgcn_mfma_f32_16x16x32_bf16(Ah[fi], Bl[fj], acc[fi][fj], 0, 0, 0);
    #pragma unroll
    for (int f = 0; f < 4; ++f) Am[f] = LDFRAG(0, ra[f], 4);
    #pragma unroll
    for (int fi = 0; fi < 4; ++fi)
      #pragma unroll
      for (int fj = 0; fj < 4; ++fj)
        acc[fi][fj] = __builtin_amdgcn_mfma_f32_16x16x32_bf16(Am[fi], Bh[fj], acc[fi][fj], 0, 0, 0);
    #pragma unroll
    for (int fi = 0; fi < 4; ++fi)
      #pragma unroll
      for (int fj = 0; fj < 4; ++fj)
        acc[fi][fj] = __builtin_amdgcn_mfma_f32_16x16x32_bf16(Am[fi], Bm[fj], acc[fi][fj], 0, 0, 0);
    #pragma unroll
    for (int f = 0; f < 4; ++f) Al[f] = LDFRAG(2, ra[f], 0);
    #pragma unroll
    for (int fi = 0; fi < 4; ++fi)
      #pragma unroll
      for (int fj = 0; fj < 4; ++fj)
        acc[fi][fj] = __builtin_amdgcn_mfma_f32_16x16x32_bf16(Al[fi], Bh[fj], acc[fi][fj], 0, 0, 0);
    __syncthreads();
  }
  #undef LDFRAG

  const int rq = (lane >> 4) << 2;
  if (MODE == 0){
    #pragma unroll
    for (int fj = 0; fj < 4; ++fj){
      const int gcol = col0 + wc + (fj << 4) + fr16;
      const float be = bias[gcol];
      #pragma unroll
      for (int fi = 0; fi < 4; ++fi){
        #pragma unroll
        for (int r = 0; r < 4; ++r){
          const int grow = row0 + wr + (fi << 4) + rq + r;
          float v = acc[fi][fj][r] + be;
          v = fmaxf(v, 0.f);
          acts[(size_t)grow * FEAT + gcol] = v;
        }
      }
    }
  } else {
    float be[4], wk[4];
    #pragma unroll
    for (int fj = 0; fj < 4; ++fj){
      const int gcol = col0 + wc + (fj << 4) + fr16;
      be[fj] = bias[gcol];
      wk[fj] = w2[gcol];
    }
    #pragma unroll
    for (int fi = 0; fi < 4; ++fi){
      #pragma unroll
      for (int r = 0; r < 4; ++r){
        float s = 0.f;
        #pragma unroll
        for (int fj = 0; fj < 4; ++fj){
          float h = fmaxf(acc[fi][fj][r] + be[fj], 0.f);
          s = fmaf(h, wk[fj], s);
        }
        s += __shfl_xor(s, 1);
        s += __shfl_xor(s, 2);
        s += __shfl_xor(s, 4);
        s += __shfl_xor(s, 8);
        if (fr16 == 0){
          const int grow = row0 + wr + (fi << 4) + rq + r;
          zpart[(size_t)grow * 256 + (bx << 1) + (wc >> 6)] = s;
        }
      }
    }
  }
}

// ===========================================================================
// PATH B (fallback, proven round-1): on-the-fly split GEMM
// ===========================================================================
template<int MODE>
__global__ __launch_bounds__(256)
void gemm6(const float* __restrict__ X, const float* __restrict__ bsub,
           const float* __restrict__ W, const float* __restrict__ bias,
           const float* __restrict__ w2, float* __restrict__ acts,
           float* __restrict__ zpart)
{
  __shared__ unsigned short sA[3][128][32];
  __shared__ unsigned short sB[3][128][32];
  const int tid  = threadIdx.x;
  const int row0 = blockIdx.y << 7;
  const int col0 = blockIdx.x << 7;
  const int lane = tid & 63, wv = tid >> 6;
  const int wr = (wv & 1) << 6, wc = (wv >> 1) << 6;
  const int fr = lane & 15;
  const int gsw = (((lane >> 4) ^ ((fr >> 1) & 3)) << 3);

  f4v acc[4][4];
  #pragma unroll
  for (int i = 0; i < 4; ++i)
    #pragma unroll
    for (int j = 0; j < 4; ++j)
      acc[i][j] = (f4v){0.f, 0.f, 0.f, 0.f};

  const int rs = tid >> 3;
  const int cb = (tid & 7) << 2;
  const int gq = cb >> 3;

  for (int kt = 0; kt < DIM / 32; ++kt){
    const int k0 = kt << 5;
    #pragma unroll
    for (int i = 0; i < 4; ++i){
      const int r  = (i << 5) + rs;
      const int cs = ((gq ^ ((r >> 1) & 3)) << 3) + (cb & 7);
      {
        const float4 xv = *(const float4*)(X + (size_t)(row0 + r) * DIM + k0 + cb);
        const float4 bd = *(const float4*)(bsub + k0 + cb);
        float v0 = xv.x - bd.x, v1 = xv.y - bd.y, v2 = xv.z - bd.z, v3 = xv.w - bd.w;
        ushort4 H, M, L;
        split3(v0, H.x, M.x, L.x); split3(v1, H.y, M.y, L.y);
        split3(v2, H.z, M.z, L.z); split3(v3, H.w, M.w, L.w);
        *(ushort4*)&sA[0][r][cs] = H;
        *(ushort4*)&sA[1][r][cs] = M;
        *(ushort4*)&sA[2][r][cs] = L;
      }
      {
        const float4 wv4 = *(const float4*)(W + (size_t)(col0 + r) * DIM + k0 + cb);
        ushort4 H, M, L;
        split3(wv4.x, H.x, M.x, L.x); split3(wv4.y, H.y, M.y, L.y);
        split3(wv4.z, H.z, M.z, L.z); split3(wv4.w, H.w, M.w, L.w);
        *(ushort4*)&sB[0][r][cs] = H;
        *(ushort4*)&sB[1][r][cs] = M;
        *(ushort4*)&sB[2][r][cs] = L;
      }
    }
    __syncthreads();
    #pragma unroll
    for (int pa = 0; pa < 3; ++pa){
      s8v a[4];
      #pragma unroll
      for (int fi = 0; fi < 4; ++fi)
        a[fi] = *(const s8v*)&sA[pa][wr + (fi << 4) + fr][gsw];
      #pragma unroll
      for (int pb = 0; pb < 3 - pa; ++pb){
        s8v b[4];
        #pragma unroll
        for (int fj = 0; fj < 4; ++fj)
          b[fj] = *(const s8v*)&sB[pb][wc + (fj << 4) + fr][gsw];
        #pragma unroll
        for (int fi = 0; fi < 4; ++fi)
          #pragma unroll
          for (int fj = 0; fj < 4; ++fj)
            acc[fi][fj] = __builtin_amdgcn_mfma_f32_16x16x32_bf16(a[fi], b[fj], acc[fi][fj], 0, 0, 0);
      }
    }
    __syncthreads();
  }

  const int rq = (lane >> 4) << 2;
  if (MODE == 0){
    #pragma unroll
    for (int fj = 0; fj < 4; ++fj){
      const int gcol = col0 + wc + (fj << 4) + fr;
      const float be = bias[gcol];
      #pragma unroll
      for (int fi = 0; fi < 4; ++fi){
        #pragma unroll
        for (int r = 0; r < 4; ++r){
          const int grow = row0 + wr + (fi << 4) + rq + r;
          float v = acc[fi][fj][r] + be;
          v = fmaxf(v, 0.f);
          acts[(size_t)grow * FEAT + gcol] = v;
        }
      }
    }
  } else {
    float be[4], wk[4];
    #pragma unroll
    for (int fj = 0; fj < 4; ++fj){
      const int gcol = col0 + wc + (fj << 4) + fr;
      be[fj] = bias[gcol];
      wk[fj] = w2[gcol];
    }
    #pragma unroll
    for (int fi = 0; fi < 4; ++fi){
      #pragma unroll
      for (int r = 0; r < 4; ++r){
        float s = 0.f;
        #pragma unroll
        for (int fj = 0; fj < 4; ++fj){
          float h = fmaxf(acc[fi][fj][r] + be[fj], 0.f);
          s = fmaf(h, wk[fj], s);
        }
        s += __shfl_xor(s, 1);
        s += __shfl_xor(s, 2);
        s += __shfl_xor(s, 4);
        s += __shfl_xor(s, 8);
        if (fr == 0){
          const int grow = row0 + wr + (fi << 4) + rq + r;
          zpart[(size_t)grow * 256 + (blockIdx.x << 1) + (wc >> 6)] = s;
        }
      }
    }
  }
}

// ===========================================================================
// shared tail kernels
// ===========================================================================
__global__ __launch_bounds__(256)
void zreduce(const float* __restrict__ zpart, const float* __restrict__ bk2,
             const int* __restrict__ kp, int* __restrict__ mrow)
{
  const int row  = blockIdx.x * 4 + (threadIdx.x >> 6);
  const int lane = threadIdx.x & 63;
  const float* zp = zpart + (size_t)row * 256;
  float s = zp[lane] + zp[lane + 64] + zp[lane + 128] + zp[lane + 192];
  s += __shfl_xor(s, 1);
  s += __shfl_xor(s, 2);
  s += __shfl_xor(s, 4);
  s += __shfl_xor(s, 8);
  s += __shfl_xor(s, 16);
  s += __shfl_xor(s, 32);
  if (lane == 0){
    float z = s + bk2[0];
    float kest = 2.f * (float)(*kp) * (1.f / (1.f + expf(-z)));
    int m = (int)ceilf(kest);
    m = min(max(m, 0), 128);
    mrow[row] = m;
  }
}

__device__ __forceinline__ void radix_find(int* hist, int nbins, int need, int tid,
                                           int* out3, int* blksum)
{
  const int per  = nbins >> 8;
  const int base = tid * per;
  int bs = 0;
  for (int j = 0; j < per; ++j) bs += hist[base + j];
  blksum[tid] = bs;
  __syncthreads();
  if (tid == 0){
    int a2 = 0;
    for (int t = 255; t >= 0; --t){ int v = blksum[t]; blksum[t] = a2; a2 += v; }
  }
  __syncthreads();
  int ch = blksum[tid];
  for (int j = per - 1; j >= 0; --j){
    const int b = base + j;
    const int c = hist[b];
    if (ch < need && need <= ch + c){ out3[0] = b; out3[1] = need - ch; out3[2] = ch; }
    ch += c;
  }
  __syncthreads();
}

__global__ __launch_bounds__(256)
void select_topk(const float* __restrict__ acts, const int* __restrict__ mrow,
                 int* __restrict__ selIdx, float* __restrict__ selVal)
{
  __shared__ int hist[2048];
  __shared__ int blksum[256];
  __shared__ int out3[4];
  __shared__ unsigned listU[2048];
  __shared__ int lcnt;

  const int row = blockIdx.x, tid = threadIdx.x;
  const int m = mrow[row];
  const float* rp = acts + (size_t)row * FEAT;

  for (int i = tid; i < 2048; i += 256) hist[i] = 0;
  __syncthreads();
  for (int i = tid; i < FEAT; i += 256){
    unsigned u = __float_as_uint(rp[i]);
    if (u) atomicAdd(&hist[u >> 21], 1);
  }
  __syncthreads();
  radix_find(hist, 2048, m, tid, out3, blksum);
  const int bin1 = out3[0];
  const int rem1 = out3[1];

  if (tid == 0) lcnt = 0;
  __syncthreads();
  for (int i = tid; i < FEAT; i += 256){
    unsigned u = __float_as_uint(rp[i]);
    if ((int)(u >> 21) == bin1){
      int p = atomicAdd(&lcnt, 1);
      if (p < 2048) listU[p] = u;
    }
  }
  __syncthreads();
  const int L = min(lcnt, 2048);

  for (int i = tid; i < 2048; i += 256) hist[i] = 0;
  __syncthreads();
  for (int i = tid; i < L; i += 256) atomicAdd(&hist[(listU[i] >> 10) & 0x7FF], 1);
  __syncthreads();
  radix_find(hist, 2048, rem1, tid, out3, blksum);
  const int bin2 = out3[0];
  const int rem2 = out3[1];

  for (int i = tid; i < 1024; i += 256) hist[i] = 0;
  __syncthreads();
  for (int i = tid; i < L; i += 256){
    unsigned u = listU[i];
    if ((int)((u >> 10) & 0x7FF) == bin2) atomicAdd(&hist[u & 0x3FF], 1);
  }
  __syncthreads();
  radix_find(hist, 1024, rem2, tid, out3, blksum);
  const int bin3 = out3[0];
  const int mEq  = out3[1];

  const unsigned tbits = ((unsigned)bin1 << 21) | ((unsigned)bin2 << 10) | (unsigned)bin3;

  if (tid < 64){
    const int base = row << 7;
    int cnt = 0;
    for (int c = 0; c < 256; ++c){
      const int i = (c << 6) + tid;
      const unsigned u = __float_as_uint(rp[i]);
      const bool g = (u > tbits);
      const unsigned long long mk = __ballot(g);
      if (g){
        int pos = cnt + __popcll(mk & ((1ull << tid) - 1ull));
        selIdx[base + pos] = i;
        selVal[base + pos] = __uint_as_float(u);
      }
      cnt += __popcll(mk);
    }
    int eqs = 0;
    for (int c = 0; c < 256 && eqs < mEq; ++c){
      const int i = (c << 6) + tid;
      const unsigned u = __float_as_uint(rp[i]);
      const bool e = (u == tbits);
      const unsigned long long mk = __ballot(e);
      if (e){
        int p = eqs + __popcll(mk & ((1ull << tid) - 1ull));
        if (p < mEq){
          selIdx[base + cnt + p] = i;
          selVal[base + cnt + p] = __uint_as_float(u);
        }
      }
      eqs += __popcll(mk);
    }
  }
}

__global__ __launch_bounds__(256)
void transpose_dec(const float* __restrict__ Wd, float* __restrict__ WdT)
{
  __shared__ float t[64][65];
  const int f0 = blockIdx.x << 6, d0 = blockIdx.y << 6;
  const int tx = threadIdx.x & 15, ty = threadIdx.x >> 4;
  #pragma unroll
  for (int r = 0; r < 4; ++r){
    const int d = ty + (r << 4);
    const float4 v = *(const float4*)(Wd + (size_t)(d0 + d) * FEAT + f0 + (tx << 2));
    t[d][(tx << 2) + 0] = v.x;
    t[d][(tx << 2) + 1] = v.y;
    t[d][(tx << 2) + 2] = v.z;
    t[d][(tx << 2) + 3] = v.w;
  }
  __syncthreads();
  #pragma unroll
  for (int r = 0; r < 4; ++r){
    const int f = ty + (r << 4);
    float4 o;
    o.x = t[(tx << 2) + 0][f];
    o.y = t[(tx << 2) + 1][f];
    o.z = t[(tx << 2) + 2][f];
    o.w = t[(tx << 2) + 3][f];
    *(float4*)(WdT + (size_t)(f0 + f) * DIM + d0 + (tx << 2)) = o;
  }
}

__global__ __launch_bounds__(256)
void decode_k(const float* __restrict__ WdT, const int* __restrict__ selIdx,
              const float* __restrict__ selVal, const int* __restrict__ mrow,
              const float* __restrict__ bdec, float* __restrict__ out)
{
  __shared__ int   sI[128];
  __shared__ float sV[128];
  const int row = blockIdx.x, tid = threadIdx.x;
  const int m = mrow[row];
  if (tid < m){
    sI[tid] = selIdx[(row << 7) + tid];
    sV[tid] = selVal[(row << 7) + tid];
  }
  __syncthreads();
  const int d = tid << 3;
  float a[8];
  {
    const float4 b0 = *(const float4*)(bdec + d);
    const float4 b1 = *(const float4*)(bdec + d + 4);
    a[0] = b0.x; a[1] = b0.y; a[2] = b0.z; a[3] = b0.w;
    a[4] = b1.x; a[5] = b1.y; a[6] = b1.z; a[7] = b1.w;
  }
  for (int i = 0; i < m; ++i){
    const float v = sV[i];
    const float* wp = WdT + (size_t)sI[i] * DIM + d;
    const float4 w0 = *(const float4*)wp;
    const float4 w1 = *(const float4*)(wp + 4);
    a[0] = fmaf(v, w0.x, a[0]); a[1] = fmaf(v, w0.y, a[1]);
    a[2] = fmaf(v, w0.z, a[2]); a[3] = fmaf(v, w0.w, a[3]);
    a[4] = fmaf(v, w1.x, a[4]); a[5] = fmaf(v, w1.y, a[5]);
    a[6] = fmaf(v, w1.z, a[6]); a[7] = fmaf(v, w1.w, a[7]);
  }
  float4 o0 = {a[0], a[1], a[2], a[3]};
  float4 o1 = {a[4], a[5], a[6], a[7]};
  *(float4*)(out + (size_t)row * DIM + d)     = o0;
  *(float4*)(out + (size_t)row * DIM + d + 4) = o1;
}

// ===========================================================================
extern "C" void kernel_launch(void* const* d_in, const int* in_sizes, int n_in,
                              void* d_out, int out_size, void* d_ws, size_t ws_size,
                              hipStream_t stream)
{
  const float* x    = (const float*)d_in[0];
  const float* Wenc = (const float*)d_in[1];
  const float* benc = (const float*)d_in[2];
  const float* Wk1  = (const float*)d_in[3];
  const float* bk1  = (const float*)d_in[4];
  const float* Wk2  = (const float*)d_in[5];
  const float* bk2  = (const float*)d_in[6];
  const float* Wdec = (const float*)d_in[7];
  const float* bdec = (const float*)d_in[8];
  const int*   kp   = (const int*)d_in[9];
  float* out = (float*)d_out;

  char* ws = (char*)d_ws;
  const size_t XS_BYTES   = (size_t)BATCH * DIM * 2;      // 16 MB per plane
  const size_t ACTS_BYTES = (size_t)BATCH * FEAT * 4;     // 256 MB
  const size_t WP_BYTES   = (size_t)FEAT * DIM * 2;       // 64 MB per plane
  const size_t NEED_A = 3 * XS_BYTES + ACTS_BYTES + 3 * WP_BYTES
                      + 4194304 + 16384 + 2097152 + 2097152;

  if (ws_size >= NEED_A){
    // ---------------- PATH A: pre-split planes ----------------
    unsigned short* xs0 = (unsigned short*)ws;
    unsigned short* xs1 = (unsigned short*)(ws + XS_BYTES);
    unsigned short* xs2 = (unsigned short*)(ws + 2 * XS_BYTES);
    char* p = ws + 3 * XS_BYTES;
    float* acts = (float*)p;
    float* WdT  = (float*)p;                 // aliased after select
    p += ACTS_BYTES;
    unsigned short* wp0 = (unsigned short*)p;
    unsigned short* wp1 = (unsigned short*)(p + WP_BYTES);
    unsigned short* wp2 = (unsigned short*)(p + 2 * WP_BYTES);
    p += 3 * WP_BYTES;
    float* zpart  = (float*)p;               p += 4194304;
    int*   mrow   = (int*)p;                 p += 16384;
    int*   selIdx = (int*)p;                 p += 2097152;
    float* selVal = (float*)p;

    splitX<<<dim3(BATCH * DIM / 1024), dim3(256), 0, stream>>>(x, bdec, xs0, xs1, xs2);
    // kest GEMM first (so Wp region can be reused for Wenc planes)
    splitW<<<dim3(FEAT * DIM / 1024), dim3(256), 0, stream>>>(Wk1, wp0, wp1, wp2);
    gemmp<1><<<dim3(4096), dim3(256), 0, stream>>>(xs0, xs1, xs2, wp0, wp1, wp2,
                                                   bk1, Wk2, nullptr, zpart);
    zreduce<<<dim3(BATCH / 4), dim3(256), 0, stream>>>(zpart, bk2, kp, mrow);
    splitW<<<dim3(FEAT * DIM / 1024), dim3(256), 0, stream>>>(Wenc, wp0, wp1, wp2);
    gemmp<0><<<dim3(4096), dim3(256), 0, stream>>>(xs0, xs1, xs2, wp0, wp1, wp2,
                                                   benc, nullptr, acts, nullptr);
    select_topk<<<dim3(BATCH), dim3(256), 0, stream>>>(acts, mrow, selIdx, selVal);
    transpose_dec<<<dim3(FEAT / 64, DIM / 64), dim3(256), 0, stream>>>(Wdec, WdT);
    decode_k<<<dim3(BATCH), dim3(256), 0, stream>>>(WdT, selIdx, selVal, mrow, bdec, out);
  } else {
    // ---------------- PATH B: proven round-1 fallback ----------------
    float* acts   = (float*)ws;
    float* WdT    = (float*)ws;
    float* zpart  = (float*)(ws + ACTS_BYTES);
    int*   mrow   = (int*)  (ws + ACTS_BYTES + 4194304);
    int*   selIdx = (int*)  (ws + ACTS_BYTES + 4194304 + 16384);
    float* selVal = (float*)(ws + ACTS_BYTES + 4194304 + 16384 + 2097152);

    dim3 gg(FEAT / 128, BATCH / 128);
    gemm6<0><<<gg, dim3(256), 0, stream>>>(x, bdec, Wenc, benc, nullptr, acts, nullptr);
    gemm6<1><<<gg, dim3(256), 0, stream>>>(x, bdec, Wk1, bk1, Wk2, nullptr, zpart);
    zreduce<<<dim3(BATCH / 4), dim3(256), 0, stream>>>(zpart, bk2, kp, mrow);
    select_topk<<<dim3(BATCH), dim3(256), 0, stream>>>(acts, mrow, selIdx, selVal);
    transpose_dec<<<dim3(FEAT / 64, DIM / 64), dim3(256), 0, stream>>>(Wdec, WdT);
    decode_k<<<dim3(BATCH), dim3(256), 0, stream>>>(WdT, selIdx, selVal, mrow, bdec, out);
  }
}

// Round 4
// 3497.936 us; speedup vs baseline: 1.1989x; 1.1989x over previous
//
#include <hip/hip_runtime.h>
#include <hip/hip_bf16.h>
#include <cstdint>
#include <cstddef>

#define BATCH 4096
#define DIM   2048
#define FEAT  16384

typedef __attribute__((ext_vector_type(8))) short s8v;
typedef __attribute__((ext_vector_type(8))) _Float16 h8v;
typedef __attribute__((ext_vector_type(4))) float f4v;

__device__ __forceinline__ unsigned short f2bf(float f){
  unsigned u = __float_as_uint(f);
  unsigned r = u + 0x7FFFu + ((u >> 16) & 1u);
  return (unsigned short)(r >> 16);
}
__device__ __forceinline__ float bf2f(unsigned short h){
  return __uint_as_float(((unsigned)h) << 16);
}
__device__ __forceinline__ void split3(float v, unsigned short &h, unsigned short &m, unsigned short &l){
  h = f2bf(v);
  float r1 = v - bf2f(h);
  m = f2bf(r1);
  float r2 = r1 - bf2f(m);
  l = f2bf(r2);
}

// fp16 2-way split: v = h + l/2048 (l stored x2048 to stay in normal range)
__device__ __forceinline__ void split2(float v, unsigned short &h, unsigned short &l){
  _Float16 hf = (_Float16)v;
  _Float16 lf = (_Float16)((v - (float)hf) * 2048.0f);
  h = __builtin_bit_cast(unsigned short, hf);
  l = __builtin_bit_cast(unsigned short, lf);
}

__device__ __forceinline__ void gload16(const void* g, void* l){
  __builtin_amdgcn_global_load_lds(
      (const __attribute__((address_space(1))) void*)g,
      (__attribute__((address_space(3))) void*)l, 16, 0, 0);
}

// ===========================================================================
// PATH A: fp16 2-split planes + global_load_lds GEMM (3 MFMA products)
// ===========================================================================

// x -> 2 fp16 planes of (x - b_dec)
__global__ __launch_bounds__(256)
void splitX(const float* __restrict__ x, const float* __restrict__ bdec,
            unsigned short* __restrict__ p0, unsigned short* __restrict__ p1)
{
  const size_t i = ((size_t)blockIdx.x * 256 + threadIdx.x) * 4;
  const int col = (int)(i & (DIM - 1));
  const float4 v = *(const float4*)(x + i);
  const float4 b = *(const float4*)(bdec + col);
  float e0 = v.x - b.x, e1 = v.y - b.y, e2 = v.z - b.z, e3 = v.w - b.w;
  ushort4 H, L;
  split2(e0, H.x, L.x); split2(e1, H.y, L.y);
  split2(e2, H.z, L.z); split2(e3, H.w, L.w);
  *(ushort4*)(p0 + i) = H; *(ushort4*)(p1 + i) = L;
}

// W -> 2 fp16 planes
__global__ __launch_bounds__(256)
void splitW(const float* __restrict__ w,
            unsigned short* __restrict__ p0, unsigned short* __restrict__ p1)
{
  const size_t i = ((size_t)blockIdx.x * 256 + threadIdx.x) * 4;
  const float4 v = *(const float4*)(w + i);
  ushort4 H, L;
  split2(v.x, H.x, L.x); split2(v.y, H.y, L.y);
  split2(v.z, H.z, L.z); split2(v.w, H.w, L.w);
  *(ushort4*)(p0 + i) = H; *(ushort4*)(p1 + i) = L;
}

// Plane GEMM: C = Ah*Bh + (Ah*Bl + Al*Bh)/2048  (fp32-equivalent)
// 128x128 tile, BK=32, 4 waves (64x64/wave), global_load_lds staging,
// XOR-(r&7) 16B-group swizzle (pre-swizzled global source), 32 KB LDS.
template<int MODE>
__global__ __launch_bounds__(256, 3)
void gemmp(const unsigned short* __restrict__ Ah_, const unsigned short* __restrict__ Al_,
           const unsigned short* __restrict__ Bh_, const unsigned short* __restrict__ Bl_,
           const float* __restrict__ bias, const float* __restrict__ w2,
           float* __restrict__ acts, float* __restrict__ zpart)
{
  // [0] = Ah|Al rows, [1] = Bh|Bl rows  (128 rows x 128 bytes)
  __shared__ unsigned short sAB[2][128][64];
  const int tid  = threadIdx.x;
  const int lane = tid & 63, wv = tid >> 6;

  // per-XCD 8x8 block squares: concurrent window (~64 blk/XCD) shares
  // 8 A panels + 8 B panels; K-slice working set ~256 KB fits L2.
  const int bid = blockIdx.x;
  const int xcd = bid & 7;
  const int idx = bid >> 3;          // [0,512)
  const int sq  = idx >> 6;          // [0,8)
  const int s   = idx & 63;
  const int bx  = (xcd << 4) | ((sq & 1) << 3) | (s & 7);   // [0,128)
  const int by  = ((sq >> 1) << 3) | (s >> 3);              // [0,32)
  const int row0 = by << 7, col0 = bx << 7;

  const int wr = (wv & 1) << 6, wc = (wv >> 1) << 6;

  f4v acc[4][4], acc2[4][4];
  #pragma unroll
  for (int i = 0; i < 4; ++i)
    #pragma unroll
    for (int j = 0; j < 4; ++j){
      acc[i][j]  = (f4v){0.f, 0.f, 0.f, 0.f};
      acc2[i][j] = (f4v){0.f, 0.f, 0.f, 0.f};
    }

  // ---- staging precompute: 2 buffers x 4 issues per thread ----
  const int sr = lane >> 3;   // row within 8-row stripe
  const int gp = lane & 7;    // physical 16B group
  const unsigned short* gsrc[2][4];
  #pragma unroll
  for (int j = 0; j < 4; ++j){
    const int r  = (((wv << 2) + j) << 3) + sr;      // 0..127
    const int gl = gp ^ (r & 7);                     // logical group
    const int co = (gl & 3) << 3;                    // k-element offset
    gsrc[0][j] = ((gl < 4) ? Ah_ : Al_) + (size_t)(row0 + r) * DIM + co;
    gsrc[1][j] = ((gl < 4) ? Bh_ : Bl_) + (size_t)(col0 + r) * DIM + co;
  }

  const int fr16 = lane & 15;
  const int kg   = lane >> 4;
  int ra[4], rb[4];
  #pragma unroll
  for (int f = 0; f < 4; ++f){ ra[f] = wr + (f << 4) + fr16; rb[f] = wc + (f << 4) + fr16; }

  #define LDFRAG(b, r, hb) (*(const h8v*)&sAB[b][r][(((hb) + kg) ^ ((r) & 7)) << 3])

  for (int kt = 0; kt < DIM / 32; ++kt){
    const int ko = kt << 5;
    #pragma unroll
    for (int b = 0; b < 2; ++b)
      #pragma unroll
      for (int j = 0; j < 4; ++j)
        gload16(gsrc[b][j] + ko, &sAB[b][(((wv << 2) + j) << 3)][0]);
    __syncthreads();

    h8v Ah[4], Bh[4], Al[4], Bl[4];
    #pragma unroll
    for (int f = 0; f < 4; ++f) Ah[f] = LDFRAG(0, ra[f], 0);
    #pragma unroll
    for (int f = 0; f < 4; ++f) Bh[f] = LDFRAG(1, rb[f], 0);
    #pragma unroll
    for (int fi = 0; fi < 4; ++fi)
      #pragma unroll
      for (int fj = 0; fj < 4; ++fj)
        acc[fi][fj] = __builtin_amdgcn_mfma_f32_16x16x32_f16(Ah[fi], Bh[fj], acc[fi][fj], 0, 0, 0);
    #pragma unroll
    for (int f = 0; f < 4; ++f) Al[f] = LDFRAG(0, ra[f], 4);
    #pragma unroll
    for (int fi = 0; fi < 4; ++fi)
      #pragma unroll
      for (int fj = 0; fj < 4; ++fj)
        acc2[fi][fj] = __builtin_amdgcn_mfma_f32_16x16x32_f16(Al[fi], Bh[fj], acc2[fi][fj], 0, 0, 0);
    #pragma unroll
    for (int f = 0; f < 4; ++f) Bl[f] = LDFRAG(1, rb[f], 4);
    #pragma unroll
    for (int fi = 0; fi < 4; ++fi)
      #pragma unroll
      for (int fj = 0; fj < 4; ++fj)
        acc2[fi][fj] = __builtin_amdgcn_mfma_f32_16x16x32_f16(Ah[fi], Bl[fj], acc2[fi][fj], 0, 0, 0);
    __syncthreads();
  }
  #undef LDFRAG

  const float LSC = 1.0f / 2048.0f;
  const int rq = (lane >> 4) << 2;
  if (MODE == 0){
    #pragma unroll
    for (int fj = 0; fj < 4; ++fj){
      const int gcol = col0 + wc + (fj << 4) + fr16;
      const float be = bias[gcol];
      #pragma unroll
      for (int fi = 0; fi < 4; ++fi){
        #pragma unroll
        for (int r = 0; r < 4; ++r){
          const int grow = row0 + wr + (fi << 4) + rq + r;
          float v = acc[fi][fj][r] + LSC * acc2[fi][fj][r] + be;
          v = fmaxf(v, 0.f);
          acts[(size_t)grow * FEAT + gcol] = v;
        }
      }
    }
  } else {
    float be[4], wk[4];
    #pragma unroll
    for (int fj = 0; fj < 4; ++fj){
      const int gcol = col0 + wc + (fj << 4) + fr16;
      be[fj] = bias[gcol];
      wk[fj] = w2[gcol];
    }
    #pragma unroll
    for (int fi = 0; fi < 4; ++fi){
      #pragma unroll
      for (int r = 0; r < 4; ++r){
        float s2 = 0.f;
        #pragma unroll
        for (int fj = 0; fj < 4; ++fj){
          float h = fmaxf(acc[fi][fj][r] + LSC * acc2[fi][fj][r] + be[fj], 0.f);
          s2 = fmaf(h, wk[fj], s2);
        }
        s2 += __shfl_xor(s2, 1);
        s2 += __shfl_xor(s2, 2);
        s2 += __shfl_xor(s2, 4);
        s2 += __shfl_xor(s2, 8);
        if (fr16 == 0){
          const int grow = row0 + wr + (fi << 4) + rq + r;
          zpart[(size_t)grow * 256 + (bx << 1) + (wc >> 6)] = s2;
        }
      }
    }
  }
}

// ===========================================================================
// PATH B (fallback, proven round-1): on-the-fly bf16 3-split GEMM
// ===========================================================================
template<int MODE>
__global__ __launch_bounds__(256)
void gemm6(const float* __restrict__ X, const float* __restrict__ bsub,
           const float* __restrict__ W, const float* __restrict__ bias,
           const float* __restrict__ w2, float* __restrict__ acts,
           float* __restrict__ zpart)
{
  __shared__ unsigned short sA[3][128][32];
  __shared__ unsigned short sB[3][128][32];
  const int tid  = threadIdx.x;
  const int row0 = blockIdx.y << 7;
  const int col0 = blockIdx.x << 7;
  const int lane = tid & 63, wv = tid >> 6;
  const int wr = (wv & 1) << 6, wc = (wv >> 1) << 6;
  const int fr = lane & 15;
  const int gsw = (((lane >> 4) ^ ((fr >> 1) & 3)) << 3);

  f4v acc[4][4];
  #pragma unroll
  for (int i = 0; i < 4; ++i)
    #pragma unroll
    for (int j = 0; j < 4; ++j)
      acc[i][j] = (f4v){0.f, 0.f, 0.f, 0.f};

  const int rs = tid >> 3;
  const int cb = (tid & 7) << 2;
  const int gq = cb >> 3;

  for (int kt = 0; kt < DIM / 32; ++kt){
    const int k0 = kt << 5;
    #pragma unroll
    for (int i = 0; i < 4; ++i){
      const int r  = (i << 5) + rs;
      const int cs = ((gq ^ ((r >> 1) & 3)) << 3) + (cb & 7);
      {
        const float4 xv = *(const float4*)(X + (size_t)(row0 + r) * DIM + k0 + cb);
        const float4 bd = *(const float4*)(bsub + k0 + cb);
        float v0 = xv.x - bd.x, v1 = xv.y - bd.y, v2 = xv.z - bd.z, v3 = xv.w - bd.w;
        ushort4 H, M, L;
        split3(v0, H.x, M.x, L.x); split3(v1, H.y, M.y, L.y);
        split3(v2, H.z, M.z, L.z); split3(v3, H.w, M.w, L.w);
        *(ushort4*)&sA[0][r][cs] = H;
        *(ushort4*)&sA[1][r][cs] = M;
        *(ushort4*)&sA[2][r][cs] = L;
      }
      {
        const float4 wv4 = *(const float4*)(W + (size_t)(col0 + r) * DIM + k0 + cb);
        ushort4 H, M, L;
        split3(wv4.x, H.x, M.x, L.x); split3(wv4.y, H.y, M.y, L.y);
        split3(wv4.z, H.z, M.z, L.z); split3(wv4.w, H.w, M.w, L.w);
        *(ushort4*)&sB[0][r][cs] = H;
        *(ushort4*)&sB[1][r][cs] = M;
        *(ushort4*)&sB[2][r][cs] = L;
      }
    }
    __syncthreads();
    #pragma unroll
    for (int pa = 0; pa < 3; ++pa){
      s8v a[4];
      #pragma unroll
      for (int fi = 0; fi < 4; ++fi)
        a[fi] = *(const s8v*)&sA[pa][wr + (fi << 4) + fr][gsw];
      #pragma unroll
      for (int pb = 0; pb < 3 - pa; ++pb){
        s8v b[4];
        #pragma unroll
        for (int fj = 0; fj < 4; ++fj)
          b[fj] = *(const s8v*)&sB[pb][wc + (fj << 4) + fr][gsw];
        #pragma unroll
        for (int fi = 0; fi < 4; ++fi)
          #pragma unroll
          for (int fj = 0; fj < 4; ++fj)
            acc[fi][fj] = __builtin_amdgcn_mfma_f32_16x16x32_bf16(a[fi], b[fj], acc[fi][fj], 0, 0, 0);
      }
    }
    __syncthreads();
  }

  const int rq = (lane >> 4) << 2;
  if (MODE == 0){
    #pragma unroll
    for (int fj = 0; fj < 4; ++fj){
      const int gcol = col0 + wc + (fj << 4) + fr;
      const float be = bias[gcol];
      #pragma unroll
      for (int fi = 0; fi < 4; ++fi){
        #pragma unroll
        for (int r = 0; r < 4; ++r){
          const int grow = row0 + wr + (fi << 4) + rq + r;
          float v = acc[fi][fj][r] + be;
          v = fmaxf(v, 0.f);
          acts[(size_t)grow * FEAT + gcol] = v;
        }
      }
    }
  } else {
    float be[4], wk[4];
    #pragma unroll
    for (int fj = 0; fj < 4; ++fj){
      const int gcol = col0 + wc + (fj << 4) + fr;
      be[fj] = bias[gcol];
      wk[fj] = w2[gcol];
    }
    #pragma unroll
    for (int fi = 0; fi < 4; ++fi){
      #pragma unroll
      for (int r = 0; r < 4; ++r){
        float s = 0.f;
        #pragma unroll
        for (int fj = 0; fj < 4; ++fj){
          float h = fmaxf(acc[fi][fj][r] + be[fj], 0.f);
          s = fmaf(h, wk[fj], s);
        }
        s += __shfl_xor(s, 1);
        s += __shfl_xor(s, 2);
        s += __shfl_xor(s, 4);
        s += __shfl_xor(s, 8);
        if (fr == 0){
          const int grow = row0 + wr + (fi << 4) + rq + r;
          zpart[(size_t)grow * 256 + (blockIdx.x << 1) + (wc >> 6)] = s;
        }
      }
    }
  }
}

// ===========================================================================
// shared tail kernels
// ===========================================================================
__global__ __launch_bounds__(256)
void zreduce(const float* __restrict__ zpart, const float* __restrict__ bk2,
             const int* __restrict__ kp, int* __restrict__ mrow)
{
  const int row  = blockIdx.x * 4 + (threadIdx.x >> 6);
  const int lane = threadIdx.x & 63;
  const float* zp = zpart + (size_t)row * 256;
  float s = zp[lane] + zp[lane + 64] + zp[lane + 128] + zp[lane + 192];
  s += __shfl_xor(s, 1);
  s += __shfl_xor(s, 2);
  s += __shfl_xor(s, 4);
  s += __shfl_xor(s, 8);
  s += __shfl_xor(s, 16);
  s += __shfl_xor(s, 32);
  if (lane == 0){
    float z = s + bk2[0];
    float kest = 2.f * (float)(*kp) * (1.f / (1.f + expf(-z)));
    int m = (int)ceilf(kest);
    m = min(max(m, 0), 128);
    mrow[row] = m;
  }
}

__device__ __forceinline__ void radix_find(int* hist, int nbins, int need, int tid,
                                           int* out3, int* blksum)
{
  const int per  = nbins >> 8;
  const int base = tid * per;
  int bs = 0;
  for (int j = 0; j < per; ++j) bs += hist[base + j];
  blksum[tid] = bs;
  __syncthreads();
  if (tid == 0){
    int a2 = 0;
    for (int t = 255; t >= 0; --t){ int v = blksum[t]; blksum[t] = a2; a2 += v; }
  }
  __syncthreads();
  int ch = blksum[tid];
  for (int j = per - 1; j >= 0; --j){
    const int b = base + j;
    const int c = hist[b];
    if (ch < need && need <= ch + c){ out3[0] = b; out3[1] = need - ch; out3[2] = ch; }
    ch += c;
  }
  __syncthreads();
}

__global__ __launch_bounds__(256)
void select_topk(const float* __restrict__ acts, const int* __restrict__ mrow,
                 int* __restrict__ selIdx, float* __restrict__ selVal)
{
  __shared__ int hist[2048];
  __shared__ int blksum[256];
  __shared__ int out3[4];
  __shared__ unsigned listU[2048];
  __shared__ int lcnt;

  const int row = blockIdx.x, tid = threadIdx.x;
  const int m = mrow[row];
  const float* rp = acts + (size_t)row * FEAT;

  for (int i = tid; i < 2048; i += 256) hist[i] = 0;
  __syncthreads();
  for (int i = tid; i < FEAT; i += 256){
    unsigned u = __float_as_uint(rp[i]);
    if (u) atomicAdd(&hist[u >> 21], 1);
  }
  __syncthreads();
  radix_find(hist, 2048, m, tid, out3, blksum);
  const int bin1 = out3[0];
  const int rem1 = out3[1];

  if (tid == 0) lcnt = 0;
  __syncthreads();
  for (int i = tid; i < FEAT; i += 256){
    unsigned u = __float_as_uint(rp[i]);
    if ((int)(u >> 21) == bin1){
      int p = atomicAdd(&lcnt, 1);
      if (p < 2048) listU[p] = u;
    }
  }
  __syncthreads();
  const int L = min(lcnt, 2048);

  for (int i = tid; i < 2048; i += 256) hist[i] = 0;
  __syncthreads();
  for (int i = tid; i < L; i += 256) atomicAdd(&hist[(listU[i] >> 10) & 0x7FF], 1);
  __syncthreads();
  radix_find(hist, 2048, rem1, tid, out3, blksum);
  const int bin2 = out3[0];
  const int rem2 = out3[1];

  for (int i = tid; i < 1024; i += 256) hist[i] = 0;
  __syncthreads();
  for (int i = tid; i < L; i += 256){
    unsigned u = listU[i];
    if ((int)((u >> 10) & 0x7FF) == bin2) atomicAdd(&hist[u & 0x3FF], 1);
  }
  __syncthreads();
  radix_find(hist, 1024, rem2, tid, out3, blksum);
  const int bin3 = out3[0];
  const int mEq  = out3[1];

  const unsigned tbits = ((unsigned)bin1 << 21) | ((unsigned)bin2 << 10) | (unsigned)bin3;

  if (tid < 64){
    const int base = row << 7;
    int cnt = 0;
    for (int c = 0; c < 256; ++c){
      const int i = (c << 6) + tid;
      const unsigned u = __float_as_uint(rp[i]);
      const bool g = (u > tbits);
      const unsigned long long mk = __ballot(g);
      if (g){
        int pos = cnt + __popcll(mk & ((1ull << tid) - 1ull));
        selIdx[base + pos] = i;
        selVal[base + pos] = __uint_as_float(u);
      }
      cnt += __popcll(mk);
    }
    int eqs = 0;
    for (int c = 0; c < 256 && eqs < mEq; ++c){
      const int i = (c << 6) + tid;
      const unsigned u = __float_as_uint(rp[i]);
      const bool e = (u == tbits);
      const unsigned long long mk = __ballot(e);
      if (e){
        int p = eqs + __popcll(mk & ((1ull << tid) - 1ull));
        if (p < mEq){
          selIdx[base + cnt + p] = i;
          selVal[base + cnt + p] = __uint_as_float(u);
        }
      }
      eqs += __popcll(mk);
    }
  }
}

__global__ __launch_bounds__(256)
void transpose_dec(const float* __restrict__ Wd, float* __restrict__ WdT)
{
  __shared__ float t[64][65];
  const int f0 = blockIdx.x << 6, d0 = blockIdx.y << 6;
  const int tx = threadIdx.x & 15, ty = threadIdx.x >> 4;
  #pragma unroll
  for (int r = 0; r < 4; ++r){
    const int d = ty + (r << 4);
    const float4 v = *(const float4*)(Wd + (size_t)(d0 + d) * FEAT + f0 + (tx << 2));
    t[d][(tx << 2) + 0] = v.x;
    t[d][(tx << 2) + 1] = v.y;
    t[d][(tx << 2) + 2] = v.z;
    t[d][(tx << 2) + 3] = v.w;
  }
  __syncthreads();
  #pragma unroll
  for (int r = 0; r < 4; ++r){
    const int f = ty + (r << 4);
    float4 o;
    o.x = t[(tx << 2) + 0][f];
    o.y = t[(tx << 2) + 1][f];
    o.z = t[(tx << 2) + 2][f];
    o.w = t[(tx << 2) + 3][f];
    *(float4*)(WdT + (size_t)(f0 + f) * DIM + d0 + (tx << 2)) = o;
  }
}

__global__ __launch_bounds__(256)
void decode_k(const float* __restrict__ WdT, const int* __restrict__ selIdx,
              const float* __restrict__ selVal, const int* __restrict__ mrow,
              const float* __restrict__ bdec, float* __restrict__ out)
{
  __shared__ int   sI[128];
  __shared__ float sV[128];
  const int row = blockIdx.x, tid = threadIdx.x;
  const int m = mrow[row];
  if (tid < m){
    sI[tid] = selIdx[(row << 7) + tid];
    sV[tid] = selVal[(row << 7) + tid];
  }
  __syncthreads();
  const int d = tid << 3;
  float a[8];
  {
    const float4 b0 = *(const float4*)(bdec + d);
    const float4 b1 = *(const float4*)(bdec + d + 4);
    a[0] = b0.x; a[1] = b0.y; a[2] = b0.z; a[3] = b0.w;
    a[4] = b1.x; a[5] = b1.y; a[6] = b1.z; a[7] = b1.w;
  }
  for (int i = 0; i < m; ++i){
    const float v = sV[i];
    const float* wp = WdT + (size_t)sI[i] * DIM + d;
    const float4 w0 = *(const float4*)wp;
    const float4 w1 = *(const float4*)(wp + 4);
    a[0] = fmaf(v, w0.x, a[0]); a[1] = fmaf(v, w0.y, a[1]);
    a[2] = fmaf(v, w0.z, a[2]); a[3] = fmaf(v, w0.w, a[3]);
    a[4] = fmaf(v, w1.x, a[4]); a[5] = fmaf(v, w1.y, a[5]);
    a[6] = fmaf(v, w1.z, a[6]); a[7] = fmaf(v, w1.w, a[7]);
  }
  float4 o0 = {a[0], a[1], a[2], a[3]};
  float4 o1 = {a[4], a[5], a[6], a[7]};
  *(float4*)(out + (size_t)row * DIM + d)     = o0;
  *(float4*)(out + (size_t)row * DIM + d + 4) = o1;
}

// ===========================================================================
extern "C" void kernel_launch(void* const* d_in, const int* in_sizes, int n_in,
                              void* d_out, int out_size, void* d_ws, size_t ws_size,
                              hipStream_t stream)
{
  const float* x    = (const float*)d_in[0];
  const float* Wenc = (const float*)d_in[1];
  const float* benc = (const float*)d_in[2];
  const float* Wk1  = (const float*)d_in[3];
  const float* bk1  = (const float*)d_in[4];
  const float* Wk2  = (const float*)d_in[5];
  const float* bk2  = (const float*)d_in[6];
  const float* Wdec = (const float*)d_in[7];
  const float* bdec = (const float*)d_in[8];
  const int*   kp   = (const int*)d_in[9];
  float* out = (float*)d_out;

  char* ws = (char*)d_ws;
  const size_t XS_BYTES   = (size_t)BATCH * DIM * 2;      // 16 MB per plane
  const size_t ACTS_BYTES = (size_t)BATCH * FEAT * 4;     // 256 MB
  const size_t WP_BYTES   = (size_t)FEAT * DIM * 2;       // 64 MB per plane
  const size_t NEED_A = 2 * XS_BYTES + ACTS_BYTES + 2 * WP_BYTES
                      + 4194304 + 16384 + 2097152 + 2097152;

  if (ws_size >= NEED_A){
    // ---------------- PATH A: fp16 2-split planes ----------------
    unsigned short* xs0 = (unsigned short*)ws;
    unsigned short* xs1 = (unsigned short*)(ws + XS_BYTES);
    char* p = ws + 2 * XS_BYTES;
    float* acts = (float*)p;
    float* WdT  = (float*)p;                 // aliased after select
    p += ACTS_BYTES;
    unsigned short* wp0 = (unsigned short*)p;
    unsigned short* wp1 = (unsigned short*)(p + WP_BYTES);
    p += 2 * WP_BYTES;
    float* zpart  = (float*)p;               p += 4194304;
    int*   mrow   = (int*)p;                 p += 16384;
    int*   selIdx = (int*)p;                 p += 2097152;
    float* selVal = (float*)p;

    splitX<<<dim3(BATCH * DIM / 1024), dim3(256), 0, stream>>>(x, bdec, xs0, xs1);
    // kest GEMM first (so Wp region can be reused for Wenc planes)
    splitW<<<dim3(FEAT * DIM / 1024), dim3(256), 0, stream>>>(Wk1, wp0, wp1);
    gemmp<1><<<dim3(4096), dim3(256), 0, stream>>>(xs0, xs1, wp0, wp1,
                                                   bk1, Wk2, nullptr, zpart);
    zreduce<<<dim3(BATCH / 4), dim3(256), 0, stream>>>(zpart, bk2, kp, mrow);
    splitW<<<dim3(FEAT * DIM / 1024), dim3(256), 0, stream>>>(Wenc, wp0, wp1);
    gemmp<0><<<dim3(4096), dim3(256), 0, stream>>>(xs0, xs1, wp0, wp1,
                                                   benc, nullptr, acts, nullptr);
    select_topk<<<dim3(BATCH), dim3(256), 0, stream>>>(acts, mrow, selIdx, selVal);
    transpose_dec<<<dim3(FEAT / 64, DIM / 64), dim3(256), 0, stream>>>(Wdec, WdT);
    decode_k<<<dim3(BATCH), dim3(256), 0, stream>>>(WdT, selIdx, selVal, mrow, bdec, out);
  } else {
    // ---------------- PATH B: proven round-1 fallback ----------------
    float* acts   = (float*)ws;
    float* WdT    = (float*)ws;
    float* zpart  = (float*)(ws + ACTS_BYTES);
    int*   mrow   = (int*)  (ws + ACTS_BYTES + 4194304);
    int*   selIdx = (int*)  (ws + ACTS_BYTES + 4194304 + 16384);
    float* selVal = (float*)(ws + ACTS_BYTES + 4194304 + 16384 + 2097152);

    dim3 gg(FEAT / 128, BATCH / 128);
    gemm6<0><<<gg, dim3(256), 0, stream>>>(x, bdec, Wenc, benc, nullptr, acts, nullptr);
    gemm6<1><<<gg, dim3(256), 0, stream>>>(x, bdec, Wk1, bk1, Wk2, nullptr, zpart);
    zreduce<<<dim3(BATCH / 4), dim3(256), 0, stream>>>(zpart, bk2, kp, mrow);
    select_topk<<<dim3(BATCH), dim3(256), 0, stream>>>(acts, mrow, selIdx, selVal);
    transpose_dec<<<dim3(FEAT / 64, DIM / 64), dim3(256), 0, stream>>>(Wdec, WdT);
    decode_k<<<dim3(BATCH), dim3(256), 0, stream>>>(WdT, selIdx, selVal, mrow, bdec, out);
  }
}

// Round 5
// 2270.854 us; speedup vs baseline: 1.8467x; 1.5404x over previous
//
#include <hip/hip_runtime.h>
#include <hip/hip_bf16.h>
#include <cstdint>
#include <cstddef>

#define BATCH 4096
#define DIM   2048
#define FEAT  16384

typedef __attribute__((ext_vector_type(8))) short s8v;
typedef __attribute__((ext_vector_type(8))) _Float16 h8v;
typedef __attribute__((ext_vector_type(4))) float f4v;

__device__ __forceinline__ unsigned short f2bf(float f){
  unsigned u = __float_as_uint(f);
  unsigned r = u + 0x7FFFu + ((u >> 16) & 1u);
  return (unsigned short)(r >> 16);
}
__device__ __forceinline__ float bf2f(unsigned short h){
  return __uint_as_float(((unsigned)h) << 16);
}
__device__ __forceinline__ void split3(float v, unsigned short &h, unsigned short &m, unsigned short &l){
  h = f2bf(v);
  float r1 = v - bf2f(h);
  m = f2bf(r1);
  float r2 = r1 - bf2f(m);
  l = f2bf(r2);
}

// fp16 2-way split: v = h + l/2048 (l stored x2048 to stay in normal range)
__device__ __forceinline__ void split2(float v, unsigned short &h, unsigned short &l){
  _Float16 hf = (_Float16)v;
  _Float16 lf = (_Float16)((v - (float)hf) * 2048.0f);
  h = __builtin_bit_cast(unsigned short, hf);
  l = __builtin_bit_cast(unsigned short, lf);
}

__device__ __forceinline__ void gload16(const void* g, void* l){
  __builtin_amdgcn_global_load_lds(
      (const __attribute__((address_space(1))) void*)g,
      (__attribute__((address_space(3))) void*)l, 16, 0, 0);
}

// ===========================================================================
// PATH A: fp16 2-split planes + pipelined global_load_lds GEMM (3 products)
// ===========================================================================

// x -> 2 fp16 planes of (x - b_dec)
__global__ __launch_bounds__(256)
void splitX(const float* __restrict__ x, const float* __restrict__ bdec,
            unsigned short* __restrict__ p0, unsigned short* __restrict__ p1)
{
  const size_t i = ((size_t)blockIdx.x * 256 + threadIdx.x) * 4;
  const int col = (int)(i & (DIM - 1));
  const float4 v = *(const float4*)(x + i);
  const float4 b = *(const float4*)(bdec + col);
  float e0 = v.x - b.x, e1 = v.y - b.y, e2 = v.z - b.z, e3 = v.w - b.w;
  ushort4 H, L;
  split2(e0, H.x, L.x); split2(e1, H.y, L.y);
  split2(e2, H.z, L.z); split2(e3, H.w, L.w);
  *(ushort4*)(p0 + i) = H; *(ushort4*)(p1 + i) = L;
}

// W -> 2 fp16 planes
__global__ __launch_bounds__(256)
void splitW(const float* __restrict__ w,
            unsigned short* __restrict__ p0, unsigned short* __restrict__ p1)
{
  const size_t i = ((size_t)blockIdx.x * 256 + threadIdx.x) * 4;
  const float4 v = *(const float4*)(w + i);
  ushort4 H, L;
  split2(v.x, H.x, L.x); split2(v.y, H.y, L.y);
  split2(v.z, H.z, L.z); split2(v.w, H.w, L.w);
  *(ushort4*)(p0 + i) = H; *(ushort4*)(p1 + i) = L;
}

// Plane GEMM: C = Ah*Bh + (Ah*Bl + Al*Bh)/2048  (fp32-equivalent)
// 128x128 tile, BK=32, 4 waves, LDS double-buffer + T3-min pipeline
// (STAGE next -> MFMA current -> one barrier). Swapped-operand MFMA
// (mfma(b,a) = C^T frag) so each lane stores float4 along the row.
template<int MODE>
__global__ __launch_bounds__(256, 2)
void gemmp(const unsigned short* __restrict__ Ah_, const unsigned short* __restrict__ Al_,
           const unsigned short* __restrict__ Bh_, const unsigned short* __restrict__ Bl_,
           const float* __restrict__ bias, const float* __restrict__ w2,
           float* __restrict__ acts, float* __restrict__ zpart)
{
  // [buf][0]=Ah|Al rows, [buf][1]=Bh|Bl rows (128 rows x 128 bytes each)
  __shared__ unsigned short sAB[2][2][128][64];
  const int tid  = threadIdx.x;
  const int lane = tid & 63, wv = tid >> 6;

  // per-XCD 8x8 block squares (round-4 walk; FETCH was acceptable)
  const int bid = blockIdx.x;
  const int xcd = bid & 7;
  const int idx = bid >> 3;          // [0,512)
  const int sq  = idx >> 6;          // [0,8)
  const int s   = idx & 63;
  const int bx  = (xcd << 4) | ((sq & 1) << 3) | (s & 7);   // [0,128)
  const int by  = ((sq >> 1) << 3) | (s >> 3);              // [0,32)
  const int row0 = by << 7, col0 = bx << 7;

  const int wr = (wv & 1) << 6, wc = (wv >> 1) << 6;

  f4v acc[4][4], acc2[4][4];
  #pragma unroll
  for (int i = 0; i < 4; ++i)
    #pragma unroll
    for (int j = 0; j < 4; ++j){
      acc[i][j]  = (f4v){0.f, 0.f, 0.f, 0.f};
      acc2[i][j] = (f4v){0.f, 0.f, 0.f, 0.f};
    }

  // ---- staging precompute: 2 tiles x 4 issues per thread ----
  const int sr = lane >> 3;   // row within 8-row stripe
  const int gp = lane & 7;    // physical 16B group
  const unsigned short* gsrc[2][4];
  #pragma unroll
  for (int j = 0; j < 4; ++j){
    const int r  = (((wv << 2) + j) << 3) + sr;      // 0..127
    const int gl = gp ^ (r & 7);                     // logical group
    const int co = (gl & 3) << 3;                    // k-element offset
    gsrc[0][j] = ((gl < 4) ? Ah_ : Al_) + (size_t)(row0 + r) * DIM + co;
    gsrc[1][j] = ((gl < 4) ? Bh_ : Bl_) + (size_t)(col0 + r) * DIM + co;
  }

  const int fr16 = lane & 15;
  const int kg   = lane >> 4;
  int ra[4], rb[4];
  #pragma unroll
  for (int f = 0; f < 4; ++f){ ra[f] = wr + (f << 4) + fr16; rb[f] = wc + (f << 4) + fr16; }

  #define LDFRAG(bf, b, r, hb) (*(const h8v*)&sAB[bf][b][r][(((hb) + kg) ^ ((r) & 7)) << 3])
  #define STAGE(bf, ko)                                                      \
    {                                                                        \
      _Pragma("unroll")                                                      \
      for (int b = 0; b < 2; ++b)                                            \
        _Pragma("unroll")                                                    \
        for (int j = 0; j < 4; ++j)                                          \
          gload16(gsrc[b][j] + (ko), &sAB[bf][b][(((wv << 2) + j) << 3)][0]);\
    }

  int cur = 0;
  STAGE(0, 0);
  __syncthreads();

  for (int kt = 0; kt < DIM / 32; ++kt){
    if (kt < DIM / 32 - 1) STAGE(cur ^ 1, (kt + 1) << 5);

    h8v Ah[4], Bh[4], Xl[4];
    #pragma unroll
    for (int f = 0; f < 4; ++f) Ah[f] = LDFRAG(cur, 0, ra[f], 0);
    #pragma unroll
    for (int f = 0; f < 4; ++f) Bh[f] = LDFRAG(cur, 1, rb[f], 0);
    #pragma unroll
    for (int fi = 0; fi < 4; ++fi)
      #pragma unroll
      for (int fj = 0; fj < 4; ++fj)
        acc[fi][fj] = __builtin_amdgcn_mfma_f32_16x16x32_f16(Bh[fj], Ah[fi], acc[fi][fj], 0, 0, 0);
    #pragma unroll
    for (int f = 0; f < 4; ++f) Xl[f] = LDFRAG(cur, 0, ra[f], 4);   // Al
    #pragma unroll
    for (int fi = 0; fi < 4; ++fi)
      #pragma unroll
      for (int fj = 0; fj < 4; ++fj)
        acc2[fi][fj] = __builtin_amdgcn_mfma_f32_16x16x32_f16(Bh[fj], Xl[fi], acc2[fi][fj], 0, 0, 0);
    #pragma unroll
    for (int f = 0; f < 4; ++f) Xl[f] = LDFRAG(cur, 1, rb[f], 4);   // Bl
    #pragma unroll
    for (int fi = 0; fi < 4; ++fi)
      #pragma unroll
      for (int fj = 0; fj < 4; ++fj)
        acc2[fi][fj] = __builtin_amdgcn_mfma_f32_16x16x32_f16(Xl[fj], Ah[fi], acc2[fi][fj], 0, 0, 0);

    __syncthreads();
    cur ^= 1;
  }
  #undef LDFRAG
  #undef STAGE

  // Swapped-operand C^T frag: lane holds C[m = lane&15][n = (lane>>4)*4 + reg]
  const float LSC = 1.0f / 2048.0f;
  const int mloc = lane & 15;
  const int nq   = (lane >> 4) << 2;   // 0,4,8,12
  if (MODE == 0){
    #pragma unroll
    for (int fi = 0; fi < 4; ++fi){
      const int grow = row0 + wr + (fi << 4) + mloc;
      #pragma unroll
      for (int fj = 0; fj < 4; ++fj){
        const int gcol = col0 + wc + (fj << 4) + nq;
        const float4 be = *(const float4*)(bias + gcol);
        f4v v;
        v[0] = fmaxf(acc[fi][fj][0] + LSC * acc2[fi][fj][0] + be.x, 0.f);
        v[1] = fmaxf(acc[fi][fj][1] + LSC * acc2[fi][fj][1] + be.y, 0.f);
        v[2] = fmaxf(acc[fi][fj][2] + LSC * acc2[fi][fj][2] + be.z, 0.f);
        v[3] = fmaxf(acc[fi][fj][3] + LSC * acc2[fi][fj][3] + be.w, 0.f);
        *(f4v*)(acts + (size_t)grow * FEAT + gcol) = v;
      }
    }
  } else {
    #pragma unroll
    for (int fi = 0; fi < 4; ++fi){
      float ssum = 0.f;
      #pragma unroll
      for (int fj = 0; fj < 4; ++fj){
        const int gcol = col0 + wc + (fj << 4) + nq;
        const float4 be = *(const float4*)(bias + gcol);
        const float4 wk = *(const float4*)(w2 + gcol);
        float h0 = fmaxf(acc[fi][fj][0] + LSC * acc2[fi][fj][0] + be.x, 0.f);
        float h1 = fmaxf(acc[fi][fj][1] + LSC * acc2[fi][fj][1] + be.y, 0.f);
        float h2 = fmaxf(acc[fi][fj][2] + LSC * acc2[fi][fj][2] + be.z, 0.f);
        float h3 = fmaxf(acc[fi][fj][3] + LSC * acc2[fi][fj][3] + be.w, 0.f);
        ssum = fmaf(h0, wk.x, ssum);
        ssum = fmaf(h1, wk.y, ssum);
        ssum = fmaf(h2, wk.z, ssum);
        ssum = fmaf(h3, wk.w, ssum);
      }
      ssum += __shfl_xor(ssum, 16);
      ssum += __shfl_xor(ssum, 32);
      if (lane < 16){
        const int grow = row0 + wr + (fi << 4) + lane;
        zpart[(size_t)grow * 256 + (bx << 1) + (wc >> 6)] = ssum;
      }
    }
  }
}

// ===========================================================================
// PATH B (fallback, proven round-1): on-the-fly bf16 3-split GEMM
// ===========================================================================
template<int MODE>
__global__ __launch_bounds__(256)
void gemm6(const float* __restrict__ X, const float* __restrict__ bsub,
           const float* __restrict__ W, const float* __restrict__ bias,
           const float* __restrict__ w2, float* __restrict__ acts,
           float* __restrict__ zpart)
{
  __shared__ unsigned short sA[3][128][32];
  __shared__ unsigned short sB[3][128][32];
  const int tid  = threadIdx.x;
  const int row0 = blockIdx.y << 7;
  const int col0 = blockIdx.x << 7;
  const int lane = tid & 63, wv = tid >> 6;
  const int wr = (wv & 1) << 6, wc = (wv >> 1) << 6;
  const int fr = lane & 15;
  const int gsw = (((lane >> 4) ^ ((fr >> 1) & 3)) << 3);

  f4v acc[4][4];
  #pragma unroll
  for (int i = 0; i < 4; ++i)
    #pragma unroll
    for (int j = 0; j < 4; ++j)
      acc[i][j] = (f4v){0.f, 0.f, 0.f, 0.f};

  const int rs = tid >> 3;
  const int cb = (tid & 7) << 2;
  const int gq = cb >> 3;

  for (int kt = 0; kt < DIM / 32; ++kt){
    const int k0 = kt << 5;
    #pragma unroll
    for (int i = 0; i < 4; ++i){
      const int r  = (i << 5) + rs;
      const int cs = ((gq ^ ((r >> 1) & 3)) << 3) + (cb & 7);
      {
        const float4 xv = *(const float4*)(X + (size_t)(row0 + r) * DIM + k0 + cb);
        const float4 bd = *(const float4*)(bsub + k0 + cb);
        float v0 = xv.x - bd.x, v1 = xv.y - bd.y, v2 = xv.z - bd.z, v3 = xv.w - bd.w;
        ushort4 H, M, L;
        split3(v0, H.x, M.x, L.x); split3(v1, H.y, M.y, L.y);
        split3(v2, H.z, M.z, L.z); split3(v3, H.w, M.w, L.w);
        *(ushort4*)&sA[0][r][cs] = H;
        *(ushort4*)&sA[1][r][cs] = M;
        *(ushort4*)&sA[2][r][cs] = L;
      }
      {
        const float4 wv4 = *(const float4*)(W + (size_t)(col0 + r) * DIM + k0 + cb);
        ushort4 H, M, L;
        split3(wv4.x, H.x, M.x, L.x); split3(wv4.y, H.y, M.y, L.y);
        split3(wv4.z, H.z, M.z, L.z); split3(wv4.w, H.w, M.w, L.w);
        *(ushort4*)&sB[0][r][cs] = H;
        *(ushort4*)&sB[1][r][cs] = M;
        *(ushort4*)&sB[2][r][cs] = L;
      }
    }
    __syncthreads();
    #pragma unroll
    for (int pa = 0; pa < 3; ++pa){
      s8v a[4];
      #pragma unroll
      for (int fi = 0; fi < 4; ++fi)
        a[fi] = *(const s8v*)&sA[pa][wr + (fi << 4) + fr][gsw];
      #pragma unroll
      for (int pb = 0; pb < 3 - pa; ++pb){
        s8v b[4];
        #pragma unroll
        for (int fj = 0; fj < 4; ++fj)
          b[fj] = *(const s8v*)&sB[pb][wc + (fj << 4) + fr][gsw];
        #pragma unroll
        for (int fi = 0; fi < 4; ++fi)
          #pragma unroll
          for (int fj = 0; fj < 4; ++fj)
            acc[fi][fj] = __builtin_amdgcn_mfma_f32_16x16x32_bf16(a[fi], b[fj], acc[fi][fj], 0, 0, 0);
      }
    }
    __syncthreads();
  }

  const int rq = (lane >> 4) << 2;
  if (MODE == 0){
    #pragma unroll
    for (int fj = 0; fj < 4; ++fj){
      const int gcol = col0 + wc + (fj << 4) + fr;
      const float be = bias[gcol];
      #pragma unroll
      for (int fi = 0; fi < 4; ++fi){
        #pragma unroll
        for (int r = 0; r < 4; ++r){
          const int grow = row0 + wr + (fi << 4) + rq + r;
          float v = acc[fi][fj][r] + be;
          v = fmaxf(v, 0.f);
          acts[(size_t)grow * FEAT + gcol] = v;
        }
      }
    }
  } else {
    float be[4], wk[4];
    #pragma unroll
    for (int fj = 0; fj < 4; ++fj){
      const int gcol = col0 + wc + (fj << 4) + fr;
      be[fj] = bias[gcol];
      wk[fj] = w2[gcol];
    }
    #pragma unroll
    for (int fi = 0; fi < 4; ++fi){
      #pragma unroll
      for (int r = 0; r < 4; ++r){
        float s = 0.f;
        #pragma unroll
        for (int fj = 0; fj < 4; ++fj){
          float h = fmaxf(acc[fi][fj][r] + be[fj], 0.f);
          s = fmaf(h, wk[fj], s);
        }
        s += __shfl_xor(s, 1);
        s += __shfl_xor(s, 2);
        s += __shfl_xor(s, 4);
        s += __shfl_xor(s, 8);
        if (fr == 0){
          const int grow = row0 + wr + (fi << 4) + rq + r;
          zpart[(size_t)grow * 256 + (blockIdx.x << 1) + (wc >> 6)] = s;
        }
      }
    }
  }
}

// ===========================================================================
// shared tail kernels
// ===========================================================================
__global__ __launch_bounds__(256)
void zreduce(const float* __restrict__ zpart, const float* __restrict__ bk2,
             const int* __restrict__ kp, int* __restrict__ mrow)
{
  const int row  = blockIdx.x * 4 + (threadIdx.x >> 6);
  const int lane = threadIdx.x & 63;
  const float* zp = zpart + (size_t)row * 256;
  float s = zp[lane] + zp[lane + 64] + zp[lane + 128] + zp[lane + 192];
  s += __shfl_xor(s, 1);
  s += __shfl_xor(s, 2);
  s += __shfl_xor(s, 4);
  s += __shfl_xor(s, 8);
  s += __shfl_xor(s, 16);
  s += __shfl_xor(s, 32);
  if (lane == 0){
    float z = s + bk2[0];
    float kest = 2.f * (float)(*kp) * (1.f / (1.f + expf(-z)));
    int m = (int)ceilf(kest);
    m = min(max(m, 0), 128);
    mrow[row] = m;
  }
}

__device__ __forceinline__ void radix_find(int* hist, int nbins, int need, int tid,
                                           int* out3, int* blksum)
{
  const int per  = nbins >> 8;
  const int base = tid * per;
  int bs = 0;
  for (int j = 0; j < per; ++j) bs += hist[base + j];
  blksum[tid] = bs;
  __syncthreads();
  if (tid == 0){
    int a2 = 0;
    for (int t = 255; t >= 0; --t){ int v = blksum[t]; blksum[t] = a2; a2 += v; }
  }
  __syncthreads();
  int ch = blksum[tid];
  for (int j = per - 1; j >= 0; --j){
    const int b = base + j;
    const int c = hist[b];
    if (ch < need && need <= ch + c){ out3[0] = b; out3[1] = need - ch; out3[2] = ch; }
    ch += c;
  }
  __syncthreads();
}

__global__ __launch_bounds__(256)
void select_topk(const float* __restrict__ acts, const int* __restrict__ mrow,
                 int* __restrict__ selIdx, float* __restrict__ selVal)
{
  __shared__ int hist[2048];
  __shared__ int blksum[256];
  __shared__ int out3[4];
  __shared__ unsigned listU[2048];
  __shared__ int lcnt;

  const int row = blockIdx.x, tid = threadIdx.x;
  const int m = mrow[row];
  const float* rp = acts + (size_t)row * FEAT;

  for (int i = tid; i < 2048; i += 256) hist[i] = 0;
  __syncthreads();
  for (int i = tid; i < FEAT; i += 256){
    unsigned u = __float_as_uint(rp[i]);
    if (u) atomicAdd(&hist[u >> 21], 1);
  }
  __syncthreads();
  radix_find(hist, 2048, m, tid, out3, blksum);
  const int bin1 = out3[0];
  const int rem1 = out3[1];

  if (tid == 0) lcnt = 0;
  __syncthreads();
  for (int i = tid; i < FEAT; i += 256){
    unsigned u = __float_as_uint(rp[i]);
    if ((int)(u >> 21) == bin1){
      int p = atomicAdd(&lcnt, 1);
      if (p < 2048) listU[p] = u;
    }
  }
  __syncthreads();
  const int L = min(lcnt, 2048);

  for (int i = tid; i < 2048; i += 256) hist[i] = 0;
  __syncthreads();
  for (int i = tid; i < L; i += 256) atomicAdd(&hist[(listU[i] >> 10) & 0x7FF], 1);
  __syncthreads();
  radix_find(hist, 2048, rem1, tid, out3, blksum);
  const int bin2 = out3[0];
  const int rem2 = out3[1];

  for (int i = tid; i < 1024; i += 256) hist[i] = 0;
  __syncthreads();
  for (int i = tid; i < L; i += 256){
    unsigned u = listU[i];
    if ((int)((u >> 10) & 0x7FF) == bin2) atomicAdd(&hist[u & 0x3FF], 1);
  }
  __syncthreads();
  radix_find(hist, 1024, rem2, tid, out3, blksum);
  const int bin3 = out3[0];
  const int mEq  = out3[1];

  const unsigned tbits = ((unsigned)bin1 << 21) | ((unsigned)bin2 << 10) | (unsigned)bin3;

  if (tid < 64){
    const int base = row << 7;
    int cnt = 0;
    for (int c = 0; c < 256; ++c){
      const int i = (c << 6) + tid;
      const unsigned u = __float_as_uint(rp[i]);
      const bool g = (u > tbits);
      const unsigned long long mk = __ballot(g);
      if (g){
        int pos = cnt + __popcll(mk & ((1ull << tid) - 1ull));
        selIdx[base + pos] = i;
        selVal[base + pos] = __uint_as_float(u);
      }
      cnt += __popcll(mk);
    }
    int eqs = 0;
    for (int c = 0; c < 256 && eqs < mEq; ++c){
      const int i = (c << 6) + tid;
      const unsigned u = __float_as_uint(rp[i]);
      const bool e = (u == tbits);
      const unsigned long long mk = __ballot(e);
      if (e){
        int p = eqs + __popcll(mk & ((1ull << tid) - 1ull));
        if (p < mEq){
          selIdx[base + cnt + p] = i;
          selVal[base + cnt + p] = __uint_as_float(u);
        }
      }
      eqs += __popcll(mk);
    }
  }
}

__global__ __launch_bounds__(256)
void transpose_dec(const float* __restrict__ Wd, float* __restrict__ WdT)
{
  __shared__ float t[64][65];
  const int f0 = blockIdx.x << 6, d0 = blockIdx.y << 6;
  const int tx = threadIdx.x & 15, ty = threadIdx.x >> 4;
  #pragma unroll
  for (int r = 0; r < 4; ++r){
    const int d = ty + (r << 4);
    const float4 v = *(const float4*)(Wd + (size_t)(d0 + d) * FEAT + f0 + (tx << 2));
    t[d][(tx << 2) + 0] = v.x;
    t[d][(tx << 2) + 1] = v.y;
    t[d][(tx << 2) + 2] = v.z;
    t[d][(tx << 2) + 3] = v.w;
  }
  __syncthreads();
  #pragma unroll
  for (int r = 0; r < 4; ++r){
    const int f = ty + (r << 4);
    float4 o;
    o.x = t[(tx << 2) + 0][f];
    o.y = t[(tx << 2) + 1][f];
    o.z = t[(tx << 2) + 2][f];
    o.w = t[(tx << 2) + 3][f];
    *(float4*)(WdT + (size_t)(f0 + f) * DIM + d0 + (tx << 2)) = o;
  }
}

__global__ __launch_bounds__(256)
void decode_k(const float* __restrict__ WdT, const int* __restrict__ selIdx,
              const float* __restrict__ selVal, const int* __restrict__ mrow,
              const float* __restrict__ bdec, float* __restrict__ out)
{
  __shared__ int   sI[128];
  __shared__ float sV[128];
  const int row = blockIdx.x, tid = threadIdx.x;
  const int m = mrow[row];
  if (tid < m){
    sI[tid] = selIdx[(row << 7) + tid];
    sV[tid] = selVal[(row << 7) + tid];
  }
  __syncthreads();
  const int d = tid << 3;
  float a[8];
  {
    const float4 b0 = *(const float4*)(bdec + d);
    const float4 b1 = *(const float4*)(bdec + d + 4);
    a[0] = b0.x; a[1] = b0.y; a[2] = b0.z; a[3] = b0.w;
    a[4] = b1.x; a[5] = b1.y; a[6] = b1.z; a[7] = b1.w;
  }
  for (int i = 0; i < m; ++i){
    const float v = sV[i];
    const float* wp = WdT + (size_t)sI[i] * DIM + d;
    const float4 w0 = *(const float4*)wp;
    const float4 w1 = *(const float4*)(wp + 4);
    a[0] = fmaf(v, w0.x, a[0]); a[1] = fmaf(v, w0.y, a[1]);
    a[2] = fmaf(v, w0.z, a[2]); a[3] = fmaf(v, w0.w, a[3]);
    a[4] = fmaf(v, w1.x, a[4]); a[5] = fmaf(v, w1.y, a[5]);
    a[6] = fmaf(v, w1.z, a[6]); a[7] = fmaf(v, w1.w, a[7]);
  }
  float4 o0 = {a[0], a[1], a[2], a[3]};
  float4 o1 = {a[4], a[5], a[6], a[7]};
  *(float4*)(out + (size_t)row * DIM + d)     = o0;
  *(float4*)(out + (size_t)row * DIM + d + 4) = o1;
}

// ===========================================================================
extern "C" void kernel_launch(void* const* d_in, const int* in_sizes, int n_in,
                              void* d_out, int out_size, void* d_ws, size_t ws_size,
                              hipStream_t stream)
{
  const float* x    = (const float*)d_in[0];
  const float* Wenc = (const float*)d_in[1];
  const float* benc = (const float*)d_in[2];
  const float* Wk1  = (const float*)d_in[3];
  const float* bk1  = (const float*)d_in[4];
  const float* Wk2  = (const float*)d_in[5];
  const float* bk2  = (const float*)d_in[6];
  const float* Wdec = (const float*)d_in[7];
  const float* bdec = (const float*)d_in[8];
  const int*   kp   = (const int*)d_in[9];
  float* out = (float*)d_out;

  char* ws = (char*)d_ws;
  const size_t XS_BYTES   = (size_t)BATCH * DIM * 2;      // 16 MB per plane
  const size_t ACTS_BYTES = (size_t)BATCH * FEAT * 4;     // 256 MB
  const size_t WP_BYTES   = (size_t)FEAT * DIM * 2;       // 64 MB per plane
  const size_t NEED_A = 2 * XS_BYTES + ACTS_BYTES + 2 * WP_BYTES
                      + 4194304 + 16384 + 2097152 + 2097152;

  if (ws_size >= NEED_A){
    // ---------------- PATH A: fp16 2-split planes ----------------
    unsigned short* xs0 = (unsigned short*)ws;
    unsigned short* xs1 = (unsigned short*)(ws + XS_BYTES);
    char* p = ws + 2 * XS_BYTES;
    float* acts = (float*)p;
    float* WdT  = (float*)p;                 // aliased after select
    p += ACTS_BYTES;
    unsigned short* wp0 = (unsigned short*)p;
    unsigned short* wp1 = (unsigned short*)(p + WP_BYTES);
    p += 2 * WP_BYTES;
    float* zpart  = (float*)p;               p += 4194304;
    int*   mrow   = (int*)p;                 p += 16384;
    int*   selIdx = (int*)p;                 p += 2097152;
    float* selVal = (float*)p;

    splitX<<<dim3(BATCH * DIM / 1024), dim3(256), 0, stream>>>(x, bdec, xs0, xs1);
    // kest GEMM first (so Wp region can be reused for Wenc planes)
    splitW<<<dim3(FEAT * DIM / 1024), dim3(256), 0, stream>>>(Wk1, wp0, wp1);
    gemmp<1><<<dim3(4096), dim3(256), 0, stream>>>(xs0, xs1, wp0, wp1,
                                                   bk1, Wk2, nullptr, zpart);
    zreduce<<<dim3(BATCH / 4), dim3(256), 0, stream>>>(zpart, bk2, kp, mrow);
    splitW<<<dim3(FEAT * DIM / 1024), dim3(256), 0, stream>>>(Wenc, wp0, wp1);
    gemmp<0><<<dim3(4096), dim3(256), 0, stream>>>(xs0, xs1, wp0, wp1,
                                                   benc, nullptr, acts, nullptr);
    select_topk<<<dim3(BATCH), dim3(256), 0, stream>>>(acts, mrow, selIdx, selVal);
    transpose_dec<<<dim3(FEAT / 64, DIM / 64), dim3(256), 0, stream>>>(Wdec, WdT);
    decode_k<<<dim3(BATCH), dim3(256), 0, stream>>>(WdT, selIdx, selVal, mrow, bdec, out);
  } else {
    // ---------------- PATH B: proven round-1 fallback ----------------
    float* acts   = (float*)ws;
    float* WdT    = (float*)ws;
    float* zpart  = (float*)(ws + ACTS_BYTES);
    int*   mrow   = (int*)  (ws + ACTS_BYTES + 4194304);
    int*   selIdx = (int*)  (ws + ACTS_BYTES + 4194304 + 16384);
    float* selVal = (float*)(ws + ACTS_BYTES + 4194304 + 16384 + 2097152);

    dim3 gg(FEAT / 128, BATCH / 128);
    gemm6<0><<<gg, dim3(256), 0, stream>>>(x, bdec, Wenc, benc, nullptr, acts, nullptr);
    gemm6<1><<<gg, dim3(256), 0, stream>>>(x, bdec, Wk1, bk1, Wk2, nullptr, zpart);
    zreduce<<<dim3(BATCH / 4), dim3(256), 0, stream>>>(zpart, bk2, kp, mrow);
    select_topk<<<dim3(BATCH), dim3(256), 0, stream>>>(acts, mrow, selIdx, selVal);
    transpose_dec<<<dim3(FEAT / 64, DIM / 64), dim3(256), 0, stream>>>(Wdec, WdT);
    decode_k<<<dim3(BATCH), dim3(256), 0, stream>>>(WdT, selIdx, selVal, mrow, bdec, out);
  }
}